// Round 19
// baseline (683.914 us; speedup 1.0000x reference)
//
#include <hip/hip_runtime.h>
#include <hip/hip_fp16.h>
#include <hip/hip_cooperative_groups.h>

namespace cg = cooperative_groups;

// ---------------------------------------------------------------------------
// 2-layer GCN on MI355X — single cooperative kernel with multi-dispatch
// fallback (R18 failed because hipLaunchCooperativeKernel's error was
// ignored: grid=1024 likely exceeded co-residency -> silent no-op, output
// stayed zero). R19: occupancy-clamped grid + error-checked launch +
// fallback to the proven R16 7-dispatch path; phase bodies shared.
// ---------------------------------------------------------------------------

#define NPB_SHIFT 7
#define NPB 128            // nodes per bucket
#define NBMAX 1024         // supports n <= 131072
#define EPB 4096           // edges per scatter block
#define KPB (EPB / 256)    // edges per thread in scatter block
#define CAP 4608           // fixed pairs capacity per bucket (mean+8sigma)
#define CSRSTRIDE 6656     // fixed csr segment per bucket (>= CAP + 128*15+16)

struct SharedU {
    union {
        struct { int cntA[NBMAX]; int baseB[NBMAX]; } sc;                  // scatter
        struct { int deg[NPB]; int cur[NPB]; int rowL[NPB]; int mP; } bc;  // build
    };
};

// ---- phase bodies (shared by fused kernel and fallback dispatches) --------

__device__ __forceinline__ void scatter_body(SharedU& sh, const int* __restrict__ src,
                                             const int* __restrict__ dst, int E, int NB,
                                             int* __restrict__ bucketCur,
                                             int* __restrict__ pairs) {
    const int tid = threadIdx.x;
    const int scatterBlocks = (E + EPB - 1) / EPB;
    for (int vb = blockIdx.x; vb < scatterBlocks; vb += gridDim.x) {
        for (int i = tid; i < NB; i += 256) sh.sc.cntA[i] = 0;
        __syncthreads();
        int base = vb * EPB;
        int pk_[KPB], b_[KPB];
        #pragma unroll
        for (int k = 0; k < KPB; ++k) {
            int i = base + k * 256 + tid;
            if (i < E) {
                int s = src[i], d = dst[i];
                pk_[k] = (s << NPB_SHIFT) | (d & (NPB - 1));
                b_[k] = d >> NPB_SHIFT;
                atomicAdd(&sh.sc.cntA[b_[k]], 1);
            } else {
                b_[k] = -1;
            }
        }
        __syncthreads();
        for (int i = tid; i < NB; i += 256) {
            int c = sh.sc.cntA[i];
            sh.sc.baseB[i] = c ? atomicAdd(&bucketCur[i], c) : 0;
            sh.sc.cntA[i] = 0;
        }
        __syncthreads();
        #pragma unroll
        for (int k = 0; k < KPB; ++k) {
            if (b_[k] >= 0) {
                int off = atomicAdd(&sh.sc.cntA[b_[k]], 1);
                pairs[b_[k] * CAP + sh.sc.baseB[b_[k]] + off] = pk_[k];
            }
        }
        __syncthreads();
    }
}

__device__ __forceinline__ void build_body(SharedU& sh, const int* __restrict__ pairs,
                                           const int* __restrict__ bucketCnt, int NB, int n,
                                           int2* __restrict__ rowinfo, float* __restrict__ dinv,
                                           int* __restrict__ csr) {
    const int tid = threadIdx.x;
    const int padEnt = n << NPB_SHIFT;
    for (int vb = blockIdx.x; vb < NB; vb += gridDim.x) {
        int nodeBase = vb << NPB_SHIFT;
        int nNodes = min(NPB, n - nodeBase);
        int eBeg = vb * CAP;
        int m = min(bucketCnt[vb], CAP);
        int eEnd = eBeg + m;
        int Pb = vb * CSRSTRIDE;
        for (int i = tid; i < NPB; i += 256) { sh.bc.deg[i] = 0; sh.bc.cur[i] = 0; }
        __syncthreads();
        for (int e = eBeg + tid; e < eEnd; e += 256)
            atomicAdd(&sh.bc.deg[pairs[e] & (NPB - 1)], 1);
        __syncthreads();
        if (tid < 64) {
            int j0 = tid * 2, j1 = j0 + 1;
            int p0 = (sh.bc.deg[j0] + 15) & ~15, p1 = (sh.bc.deg[j1] + 15) & ~15;
            int s = p0 + p1;
            int xs = s;
            #pragma unroll
            for (int off = 1; off < 64; off <<= 1) {
                int y = __shfl_up(xs, off);
                if (tid >= off) xs += y;
            }
            int excl = xs - s;
            sh.bc.rowL[j0] = excl;
            sh.bc.rowL[j1] = excl + p0;
            if (tid == 63) sh.bc.mP = xs;          // padded total (<= CSRSTRIDE)
        }
        __syncthreads();
        int mP = sh.bc.mP;
        for (int j = tid; j < nNodes; j += 256) {
            rowinfo[nodeBase + j] = make_int2(Pb + sh.bc.rowL[j], (sh.bc.deg[j] + 15) & ~15);
            dinv[nodeBase + j] = 1.0f / sqrtf((float)(sh.bc.deg[j] + 1));  // +1 self-loop
        }
        for (int i = tid; i < mP; i += 256) csr[Pb + i] = padEnt;
        __syncthreads();
        for (int e = eBeg + tid; e < eEnd; e += 256) {
            int pk = pairs[e];
            int d = pk & (NPB - 1);
            int off = atomicAdd(&sh.bc.cur[d], 1);
            csr[Pb + sh.bc.rowL[d] + off] = pk & ~(NPB - 1);
        }
        __syncthreads();
    }
}

// hs[r, c] = fp16( dinv[r] * sum_k X[r,k] * W[k,c] ),  c = lane.
template <int K>
__device__ __forceinline__ void gemm_phase(const float* __restrict__ X,
                                           const float* __restrict__ W,
                                           const float* __restrict__ dinv,
                                           __half* __restrict__ out, int n) {
    const int lane = threadIdx.x & 63;
    const int wid  = threadIdx.x >> 6;
    const int nVB = (n + 15) >> 4;
    for (int gb = blockIdx.x; gb < nVB; gb += gridDim.x) {
        const int r0 = (gb * 4 + wid) * 4;
        if (r0 >= n) continue;                      // no syncs inside: safe
        float xr[4][K / 64];
        #pragma unroll
        for (int rr = 0; rr < 4; ++rr) {
            int r = min(r0 + rr, n - 1);
            #pragma unroll
            for (int j = 0; j < K / 64; ++j)
                xr[rr][j] = X[(size_t)r * K + j * 64 + lane];
        }
        float acc[4] = {0.f, 0.f, 0.f, 0.f};
        #pragma unroll
        for (int j = 0; j < K / 64; ++j) {
            #pragma unroll 8
            for (int kk = 0; kk < 64; ++kk) {
                float w = W[(size_t)(j * 64 + kk) * 64 + lane];
                #pragma unroll
                for (int rr = 0; rr < 4; ++rr) {
                    float xv = __int_as_float(
                        __builtin_amdgcn_readlane(__float_as_int(xr[rr][j]), kk));
                    acc[rr] = fmaf(xv, w, acc[rr]);
                }
            }
        }
        #pragma unroll
        for (int rr = 0; rr < 4; ++rr) {
            int r = r0 + rr;
            if (r < n) out[(size_t)r * 64 + lane] = __float2half_rn(acc[rr] * dinv[r]);
        }
    }
}

// R16 aggregate body: half-wave = one 128B fp16 row per edge-slot, 16 slots
// per iter per half (4 int4 csr loads, 16 independent __half2 gathers).
template <bool RELU>
__device__ __forceinline__ void agg_phase(const __half* __restrict__ hs,
                                          const int2* __restrict__ rowinfo,
                                          const int* __restrict__ csr,
                                          const float* __restrict__ dinv,
                                          const float* __restrict__ bias,
                                          float* __restrict__ out, int n) {
    const int lane = threadIdx.x & 63;
    const int half = lane >> 5;
    const int l32  = lane & 31;
    const int wid  = threadIdx.x >> 6;
    const char* hsb = (const char*)hs + l32 * 4;
    for (int node = blockIdx.x * 4 + wid; node < n; node += gridDim.x * 4) {
        int2 info = rowinfo[node];
        const int* base = csr + info.x;
        const int cnt = info.y;                    // multiple of 16
        float a0 = 0.f, a1 = 0.f;
        for (int i = 16 * half; i < cnt; i += 32) {
            int4 c0 = *reinterpret_cast<const int4*>(base + i);
            int4 c1 = *reinterpret_cast<const int4*>(base + i + 4);
            int4 c2 = *reinterpret_cast<const int4*>(base + i + 8);
            int4 c3 = *reinterpret_cast<const int4*>(base + i + 12);
            float2 f0 = __half22float2(*(const __half2*)(hsb + c0.x));
            float2 f1 = __half22float2(*(const __half2*)(hsb + c0.y));
            float2 f2 = __half22float2(*(const __half2*)(hsb + c0.z));
            float2 f3 = __half22float2(*(const __half2*)(hsb + c0.w));
            float2 f4 = __half22float2(*(const __half2*)(hsb + c1.x));
            float2 f5 = __half22float2(*(const __half2*)(hsb + c1.y));
            float2 f6 = __half22float2(*(const __half2*)(hsb + c1.z));
            float2 f7 = __half22float2(*(const __half2*)(hsb + c1.w));
            float2 f8 = __half22float2(*(const __half2*)(hsb + c2.x));
            float2 f9 = __half22float2(*(const __half2*)(hsb + c2.y));
            float2 fa = __half22float2(*(const __half2*)(hsb + c2.z));
            float2 fb = __half22float2(*(const __half2*)(hsb + c2.w));
            float2 fc = __half22float2(*(const __half2*)(hsb + c3.x));
            float2 fd = __half22float2(*(const __half2*)(hsb + c3.y));
            float2 fe = __half22float2(*(const __half2*)(hsb + c3.z));
            float2 ff = __half22float2(*(const __half2*)(hsb + c3.w));
            a0 += (((f0.x + f1.x) + (f2.x + f3.x)) + ((f4.x + f5.x) + (f6.x + f7.x)))
                + (((f8.x + f9.x) + (fa.x + fb.x)) + ((fc.x + fd.x) + (fe.x + ff.x)));
            a1 += (((f0.y + f1.y) + (f2.y + f3.y)) + ((f4.y + f5.y) + (f6.y + f7.y)))
                + (((f8.y + f9.y) + (fa.y + fb.y)) + ((fc.y + fd.y) + (fe.y + ff.y)));
        }
        a0 += __shfl_xor(a0, 32);
        a1 += __shfl_xor(a1, 32);
        float2 fs = __half22float2(
            *(const __half2*)((const char*)hs + ((size_t)node << 7) + l32 * 4));
        a0 += fs.x;
        a1 += fs.y;
        if (half == 0) {
            float dv = dinv[node];
            float b0 = bias[2 * l32], b1 = bias[2 * l32 + 1];
            float r0 = fmaf(a0, dv, b0);
            float r1 = fmaf(a1, dv, b1);
            if (RELU) { r0 = fmaxf(r0, 0.f); r1 = fmaxf(r1, 0.f); }
            *reinterpret_cast<float2*>(out + (size_t)node * 64 + 2 * l32) = make_float2(r0, r1);
        }
    }
}

// ---- fused cooperative kernel ---------------------------------------------

__global__ __launch_bounds__(256, 4) void fused_gcn(
    const float* __restrict__ x, const int* __restrict__ srcIdx,
    const int* __restrict__ dstIdx,
    const float* __restrict__ W1, const float* __restrict__ b1,
    const float* __restrict__ W2, const float* __restrict__ b2,
    float* __restrict__ out, int E, int n, int NB,
    int* __restrict__ bucketCur, int* __restrict__ pairs,
    int2* __restrict__ rowinfo, float* __restrict__ dinv,
    int* __restrict__ csr, float* __restrict__ hbuf, __half* __restrict__ hsbuf) {
    cg::grid_group grid = cg::this_grid();
    __shared__ SharedU sh;
    for (int i = blockIdx.x * 256 + threadIdx.x; i < NBMAX; i += gridDim.x * 256)
        bucketCur[i] = 0;
    if (blockIdx.x == 0 && threadIdx.x < 32)
        ((int*)(hsbuf + (size_t)n * 64))[threadIdx.x] = 0;
    grid.sync();
    scatter_body(sh, srcIdx, dstIdx, E, NB, bucketCur, pairs);
    grid.sync();
    build_body(sh, pairs, bucketCur, NB, n, rowinfo, dinv, csr);
    grid.sync();
    gemm_phase<128>(x, W1, dinv, hsbuf, n);
    grid.sync();
    agg_phase<true>(hsbuf, rowinfo, csr, dinv, b1, hbuf, n);
    grid.sync();
    gemm_phase<64>(hbuf, W2, dinv, hsbuf, n);
    grid.sync();
    agg_phase<false>(hsbuf, rowinfo, csr, dinv, b2, out, n);
}

// ---- fallback dispatches (R16 path, same bodies) --------------------------

__global__ __launch_bounds__(256) void zero_kernel(int* __restrict__ p, int m,
                                                   int* __restrict__ zrow) {
    int i = blockIdx.x * 256 + threadIdx.x;
    if (i < m) p[i] = 0;
    if (blockIdx.x == 0 && threadIdx.x < 32) zrow[threadIdx.x] = 0;
}

__global__ __launch_bounds__(256) void scatter_kernel(const int* __restrict__ src,
                                                      const int* __restrict__ dst, int E, int NB,
                                                      int* __restrict__ bucketCur,
                                                      int* __restrict__ pairs) {
    __shared__ SharedU sh;
    scatter_body(sh, src, dst, E, NB, bucketCur, pairs);
}

__global__ __launch_bounds__(256) void build_kernel(const int* __restrict__ pairs,
                                                    const int* __restrict__ bucketCnt, int NB, int n,
                                                    int2* __restrict__ rowinfo,
                                                    float* __restrict__ dinv,
                                                    int* __restrict__ csr) {
    __shared__ SharedU sh;
    build_body(sh, pairs, bucketCnt, NB, n, rowinfo, dinv, csr);
}

template <int K>
__global__ __launch_bounds__(256) void gemm_kernel(const float* __restrict__ X,
                                                   const float* __restrict__ W,
                                                   const float* __restrict__ dinv,
                                                   __half* __restrict__ out, int n) {
    gemm_phase<K>(X, W, dinv, out, n);
}

template <bool RELU>
__global__ __launch_bounds__(256) void agg_kernel(const __half* __restrict__ hs,
                                                  const int2* __restrict__ rowinfo,
                                                  const int* __restrict__ csr,
                                                  const float* __restrict__ dinv,
                                                  const float* __restrict__ bias,
                                                  float* __restrict__ out, int n) {
    agg_phase<RELU>(hs, rowinfo, csr, dinv, bias, out, n);
}

extern "C" void kernel_launch(void* const* d_in, const int* in_sizes, int n_in,
                              void* d_out, int out_size, void* d_ws, size_t ws_size,
                              hipStream_t stream) {
    const float* x  = (const float*)d_in[0];
    const int*   ei = (const int*)d_in[1];   // [2, E] int32
    const float* W1 = (const float*)d_in[2]; // [128, 64]
    const float* b1 = (const float*)d_in[3]; // [64]
    const float* W2 = (const float*)d_in[4]; // [64, 64]
    const float* b2 = (const float*)d_in[5]; // [64]
    float* out = (float*)d_out;

    int E = in_sizes[1] / 2;   // 1,600,000
    int n = out_size / 64;     // 50,000
    int NB = (n + NPB - 1) >> NPB_SHIFT;   // 391 buckets

    char* wsp = (char*)d_ws;
    auto carve = [&](size_t bytes) {
        char* p = wsp;
        wsp += (bytes + 255) & ~(size_t)255;
        return p;
    };
    float*  dinv      = (float*)carve((size_t)n * 4);
    int2*   rowinfo   = (int2*) carve((size_t)n * 8);
    int*    bucketCur = (int*)  carve((size_t)NBMAX * 4);
    int*    csr       = (int*)  carve((size_t)NB * CSRSTRIDE * 4);
    size_t  pairBytes = ((size_t)NB + 1) * CAP * 4;      // +1 bucket overflow slack
    size_t  featF32   = (size_t)n * 64 * 4;
    size_t  bigBytes  = pairBytes > featF32 ? pairBytes : featF32;
    char*   big       = (char*)carve(bigBytes);          // packed pairs, later hbuf
    int*    pairs     = (int*)big;
    float*  hbuf      = (float*)big;                     // pairs dead by then
    __half* hsbuf     = (__half*)carve((size_t)(n + 1) * 64 * 2);  // +1 zero row

    const int* srcIdx = ei;
    const int* dstIdx = ei + E;
    const int scatterBlocks = (E + EPB - 1) / EPB;  // 391
    const int gemmBlocks = (n + 15) / 16;           // 3125

    // occupancy-clamped cooperative grid (host-only queries, capture-safe,
    // deterministic across calls)
    int dev = 0;
    hipGetDevice(&dev);
    int numCU = 256;
    hipDeviceGetAttribute(&numCU, hipDeviceAttributeMultiprocessorCount, dev);
    int maxBlk = 0;
    hipError_t occErr = hipOccupancyMaxActiveBlocksPerMultiprocessor(&maxBlk, fused_gcn, 256, 0);
    int grid = 1024;
    if (occErr == hipSuccess && maxBlk > 0) {
        long cap = (long)maxBlk * numCU;
        if (cap < grid) grid = (int)cap;
    }

    void* args[] = {
        (void*)&x, (void*)&srcIdx, (void*)&dstIdx,
        (void*)&W1, (void*)&b1, (void*)&W2, (void*)&b2,
        (void*)&out, (void*)&E, (void*)&n, (void*)&NB,
        (void*)&bucketCur, (void*)&pairs, (void*)&rowinfo, (void*)&dinv,
        (void*)&csr, (void*)&hbuf, (void*)&hsbuf,
    };
    hipError_t err = hipLaunchCooperativeKernel((void*)fused_gcn, dim3(grid), dim3(256),
                                                args, 0, stream);
    if (err != hipSuccess) {
        // fallback: proven R16 multi-dispatch path (same bodies)
        zero_kernel<<<(NBMAX + 255) / 256, 256, 0, stream>>>(
            bucketCur, NBMAX, (int*)(hsbuf + (size_t)n * 64));
        scatter_kernel<<<scatterBlocks, 256, 0, stream>>>(srcIdx, dstIdx, E, NB, bucketCur, pairs);
        build_kernel<<<NB, 256, 0, stream>>>(pairs, bucketCur, NB, n, rowinfo, dinv, csr);
        gemm_kernel<128><<<gemmBlocks, 256, 0, stream>>>(x, W1, dinv, hsbuf, n);
        agg_kernel<true><<<(n + 3) / 4, 256, 0, stream>>>(hsbuf, rowinfo, csr, dinv, b1, hbuf, n);
        gemm_kernel<64><<<gemmBlocks, 256, 0, stream>>>(hbuf, W2, dinv, hsbuf, n);
        agg_kernel<false><<<(n + 3) / 4, 256, 0, stream>>>(hsbuf, rowinfo, csr, dinv, b2, out, n);
    }
}

// Round 20
// 161.957 us; speedup vs baseline: 4.2228x; 4.2228x over previous
//
#include <hip/hip_runtime.h>
#include <hip/hip_fp16.h>

// ---------------------------------------------------------------------------
// 2-layer GCN on MI355X (R20).
//   prep:   fixed-capacity bucket scatter -> padded CSR(64B-row byte offsets)
//           + rowinfo(beg,cnt) + dinv
//   layer:  hsA/hsB = fp16((x@W) * dinv[row]) column-split tables (gemm)
//           agg[i] = hs[i] + sum_{s->i} hs[s] in TWO column passes
//           out = agg * dinv[i] + b (+relu)   (fp32)
// R19 lesson: grid.sync() costs ~100us+ each on MI355X (fused coop kernel =
// 826us at 8.6% VALUBusy) -> back to multi-dispatch. R20 experiment: gather
// table column-split into two 3.2MB halves (each fits 4MB/XCD L2); agg does
// pass A (cols 0-31) for all its nodes then pass B, one kernel, grid=2048
// grid-stride (blocks stay roughly phase-aligned). Wave = 2 nodes (one per
// 32-lane half; 16-lane quarter reads one 64B row) -> ~20 VMEM in flight.
// ---------------------------------------------------------------------------

#define NPB_SHIFT 7
#define NPB 128            // nodes per bucket
#define NBMAX 1024         // supports n <= 131072
#define EPB 4096           // edges per scatter block
#define KPB (EPB / 256)    // edges per thread in scatter block
#define EMAX 8192          // LDS csr staging capacity per bucket (padded)
#define CAP 4608           // fixed pairs capacity per bucket (mean+8sigma)
#define CSRSTRIDE 6656     // fixed csr segment per bucket (>= CAP + 128*15+16)

__global__ __launch_bounds__(256) void zero_kernel(int* __restrict__ p, int m,
                                                   int* __restrict__ zrowA,
                                                   int* __restrict__ zrowB) {
    int i = blockIdx.x * 256 + threadIdx.x;
    if (i < m) p[i] = 0;
    if (blockIdx.x == 0 && threadIdx.x < 16) {     // 64B zero rows
        zrowA[threadIdx.x] = 0;
        zrowB[threadIdx.x] = 0;
    }
}

// Scatter packed edges pk = (src<<7)|(dst&127) into fixed-capacity bucket
// runs. bucketCur ends as per-bucket count.
__global__ __launch_bounds__(256) void bin_scatter_kernel(const int* __restrict__ src,
                                                          const int* __restrict__ dst, int E, int NB,
                                                          int* __restrict__ bucketCur,
                                                          int* __restrict__ pairs) {
    __shared__ int cntA[NBMAX];
    __shared__ int baseB[NBMAX];
    for (int i = threadIdx.x; i < NB; i += 256) cntA[i] = 0;
    __syncthreads();
    int base = blockIdx.x * EPB;
    int pk_[KPB], b_[KPB];
    #pragma unroll
    for (int k = 0; k < KPB; ++k) {
        int i = base + k * 256 + threadIdx.x;
        if (i < E) {
            int s = src[i], d = dst[i];
            pk_[k] = (s << NPB_SHIFT) | (d & (NPB - 1));
            b_[k] = d >> NPB_SHIFT;
            atomicAdd(&cntA[b_[k]], 1);
        } else {
            b_[k] = -1;
        }
    }
    __syncthreads();
    for (int i = threadIdx.x; i < NB; i += 256) {
        int c = cntA[i];
        baseB[i] = c ? atomicAdd(&bucketCur[i], c) : 0;
        cntA[i] = 0;
    }
    __syncthreads();
    #pragma unroll
    for (int k = 0; k < KPB; ++k) {
        if (b_[k] >= 0) {
            int off = atomicAdd(&cntA[b_[k]], 1);
            pairs[b_[k] * CAP + baseB[b_[k]] + off] = pk_[k];
        }
    }
}

// One block per bucket. Segments padded to multiples of 16 slots; pad slots
// hold the zero-row byte offset (n<<6). csr entry = src<<6 (64B row offset
// into the column-split tables).
__global__ __launch_bounds__(256) void build_csr_kernel(const int* __restrict__ pairs,
                                                        const int* __restrict__ bucketCnt,
                                                        int NB, int n,
                                                        int2* __restrict__ rowinfo,
                                                        float* __restrict__ dinv,
                                                        int* __restrict__ csr) {
    __shared__ int deg[NPB];
    __shared__ int cur[NPB];
    __shared__ int rowL[NPB];      // padded exclusive prefix
    __shared__ int lcsr[EMAX];
    __shared__ int s_mP;
    int b = blockIdx.x;
    int nodeBase = b << NPB_SHIFT;
    int nNodes = min(NPB, n - nodeBase);
    int eBeg = b * CAP;
    int m = min(bucketCnt[b], CAP);
    int eEnd = eBeg + m;
    int Pb = b * CSRSTRIDE;
    for (int i = threadIdx.x; i < NPB; i += 256) { deg[i] = 0; cur[i] = 0; }
    __syncthreads();
    for (int e = eBeg + threadIdx.x; e < eEnd; e += 256)
        atomicAdd(&deg[pairs[e] & (NPB - 1)], 1);
    __syncthreads();
    if (threadIdx.x < 64) {
        int j0 = threadIdx.x * 2, j1 = j0 + 1;
        int p0 = (deg[j0] + 15) & ~15, p1 = (deg[j1] + 15) & ~15;
        int s = p0 + p1;
        int x = s;
        #pragma unroll
        for (int off = 1; off < 64; off <<= 1) {
            int y = __shfl_up(x, off);
            if ((int)threadIdx.x >= off) x += y;
        }
        int excl = x - s;
        rowL[j0] = excl;
        rowL[j1] = excl + p0;
        if (threadIdx.x == 63) s_mP = x;   // padded total
    }
    __syncthreads();
    int mP = s_mP;
    for (int j = threadIdx.x; j < nNodes; j += 256) {
        rowinfo[nodeBase + j] = make_int2(Pb + rowL[j], (deg[j] + 15) & ~15);
        dinv[nodeBase + j] = 1.0f / sqrtf((float)(deg[j] + 1));  // +1 self-loop
    }
    const int padEnt = n << 6;   // zero-row byte offset (64B rows)
    if (mP <= EMAX) {
        for (int i = threadIdx.x; i < mP; i += 256) lcsr[i] = padEnt;
        __syncthreads();
        for (int e = eBeg + threadIdx.x; e < eEnd; e += 256) {
            int pk = pairs[e];
            int d = pk & (NPB - 1);
            int off = atomicAdd(&cur[d], 1);
            lcsr[rowL[d] + off] = (pk >> NPB_SHIFT) << 6;   // src*64 bytes
        }
        __syncthreads();
        for (int i = threadIdx.x; i < mP; i += 256) csr[Pb + i] = lcsr[i];
    } else {  // overflow fallback (adversarial): direct global init + scatter
        for (int i = threadIdx.x; i < mP; i += 256) csr[Pb + i] = padEnt;
        __syncthreads();
        for (int e = eBeg + threadIdx.x; e < eEnd; e += 256) {
            int pk = pairs[e];
            int d = pk & (NPB - 1);
            int off = atomicAdd(&cur[d], 1);
            csr[Pb + rowL[d] + off] = (pk >> NPB_SHIFT) << 6;
        }
    }
}

// hsA[r, c] (c<32) / hsB[r, c-32] = fp16( dinv[r] * sum_k X[r,k] * W[k,c] ).
// Wave = 4 rows. x per-lane (coalesced), broadcast at use via v_readlane;
// w via coalesced L1-resident global loads. No LDS, no spillable arrays.
template <int K>
__global__ __launch_bounds__(256) void gemm_scale_kernel(const float* __restrict__ X,
                                                         const float* __restrict__ W,
                                                         const float* __restrict__ dinv,
                                                         __half* __restrict__ hsA,
                                                         __half* __restrict__ hsB, int n) {
    const int lane = threadIdx.x & 63;
    const int wid  = threadIdx.x >> 6;
    const int r0 = (blockIdx.x * 4 + wid) * 4;
    if (r0 >= n) return;

    float xr[4][K / 64];
    #pragma unroll
    for (int rr = 0; rr < 4; ++rr) {
        int r = min(r0 + rr, n - 1);
        #pragma unroll
        for (int j = 0; j < K / 64; ++j)
            xr[rr][j] = X[(size_t)r * K + j * 64 + lane];
    }

    float acc[4] = {0.f, 0.f, 0.f, 0.f};
    #pragma unroll
    for (int j = 0; j < K / 64; ++j) {
        #pragma unroll 8
        for (int kk = 0; kk < 64; ++kk) {
            float w = W[(size_t)(j * 64 + kk) * 64 + lane];
            #pragma unroll
            for (int rr = 0; rr < 4; ++rr) {
                float xv = __int_as_float(
                    __builtin_amdgcn_readlane(__float_as_int(xr[rr][j]), kk));
                acc[rr] = fmaf(xv, w, acc[rr]);
            }
        }
    }
    __half* t = (lane < 32) ? hsA : hsB;
    const int cl = lane & 31;
    #pragma unroll
    for (int rr = 0; rr < 4; ++rr) {
        int r = r0 + rr;
        if (r < n) t[(size_t)r * 32 + cl] = __float2half_rn(acc[rr] * dinv[r]);
    }
}

// Two-pass column-split aggregate. Pass p reads table hsA/hsB (3.2MB,
// L2-resident). Wave = 2 nodes (half h owns node); within a half, quarter
// qq (16 lanes) reads one 64B row per gather; per half-iteration 16 slots =
// 2 int4 csr loads + 8 row gathers -> ~20 VMEM in flight per wave.
template <bool RELU>
__global__ __launch_bounds__(256) void aggregate_kernel(const __half* __restrict__ hsA,
                                                        const __half* __restrict__ hsB,
                                                        const int2* __restrict__ rowinfo,
                                                        const int* __restrict__ csr,
                                                        const float* __restrict__ dinv,
                                                        const float* __restrict__ bias,
                                                        float* __restrict__ out, int n) {
    const int lane = threadIdx.x & 63;
    const int h    = lane >> 5;          // half = which node
    const int qq   = (lane >> 4) & 1;    // quarter within half
    const int cl   = lane & 15;          // column-pair within 32-col table
    const int wid  = threadIdx.x >> 6;
    const int nodeBase0 = blockIdx.x * 8 + wid * 2 + h;
    const int stride = gridDim.x * 8;

    #pragma unroll
    for (int pass = 0; pass < 2; ++pass) {
        const char* tbl = (const char*)(pass ? hsB : hsA);
        const char* tl = tbl + cl * 4;
        for (int node = nodeBase0; node < n; node += stride) {
            int2 info = rowinfo[node];
            const int* base = csr + info.x + 8 * qq;   // quarter's slot stream
            const int cnt = info.y;                    // multiple of 16
            float a0 = 0.f, a1 = 0.f;
            for (int i = 0; i < cnt; i += 16) {
                int4 c0 = *reinterpret_cast<const int4*>(base + i);
                int4 c1 = *reinterpret_cast<const int4*>(base + i + 4);
                float2 f0 = __half22float2(*(const __half2*)(tl + c0.x));
                float2 f1 = __half22float2(*(const __half2*)(tl + c0.y));
                float2 f2 = __half22float2(*(const __half2*)(tl + c0.z));
                float2 f3 = __half22float2(*(const __half2*)(tl + c0.w));
                float2 f4 = __half22float2(*(const __half2*)(tl + c1.x));
                float2 f5 = __half22float2(*(const __half2*)(tl + c1.y));
                float2 f6 = __half22float2(*(const __half2*)(tl + c1.z));
                float2 f7 = __half22float2(*(const __half2*)(tl + c1.w));
                a0 += ((f0.x + f1.x) + (f2.x + f3.x)) + ((f4.x + f5.x) + (f6.x + f7.x));
                a1 += ((f0.y + f1.y) + (f2.y + f3.y)) + ((f4.y + f5.y) + (f6.y + f7.y));
            }
            // merge the two quarters of this half (lane ^ 16)
            a0 += __shfl_xor(a0, 16);
            a1 += __shfl_xor(a1, 16);
            if (qq == 0) {
                // self-loop row + bias + scale + write (16 lanes -> 128B)
                float2 fs = __half22float2(
                    *(const __half2*)(tl + ((size_t)node << 6)));
                a0 += fs.x;
                a1 += fs.y;
                float dv = dinv[node];
                float b0 = bias[pass * 32 + 2 * cl];
                float b1 = bias[pass * 32 + 2 * cl + 1];
                float r0 = fmaf(a0, dv, b0);
                float r1 = fmaf(a1, dv, b1);
                if (RELU) { r0 = fmaxf(r0, 0.f); r1 = fmaxf(r1, 0.f); }
                *reinterpret_cast<float2*>(out + (size_t)node * 64 + pass * 32 + 2 * cl) =
                    make_float2(r0, r1);
            }
        }
    }
}

extern "C" void kernel_launch(void* const* d_in, const int* in_sizes, int n_in,
                              void* d_out, int out_size, void* d_ws, size_t ws_size,
                              hipStream_t stream) {
    const float* x  = (const float*)d_in[0];
    const int*   ei = (const int*)d_in[1];   // [2, E] int32
    const float* W1 = (const float*)d_in[2]; // [128, 64]
    const float* b1 = (const float*)d_in[3]; // [64]
    const float* W2 = (const float*)d_in[4]; // [64, 64]
    const float* b2 = (const float*)d_in[5]; // [64]
    float* out = (float*)d_out;

    const int E = in_sizes[1] / 2;   // 1,600,000
    const int n = out_size / 64;     // 50,000
    const int NB = (n + NPB - 1) >> NPB_SHIFT;   // 391 buckets

    char* wsp = (char*)d_ws;
    auto carve = [&](size_t bytes) {
        char* p = wsp;
        wsp += (bytes + 255) & ~(size_t)255;
        return p;
    };
    float*  dinv      = (float*)carve((size_t)n * 4);
    int2*   rowinfo   = (int2*) carve((size_t)n * 8);
    int*    bucketCur = (int*)  carve((size_t)NBMAX * 4);
    int*    csr       = (int*)  carve((size_t)NB * CSRSTRIDE * 4);
    size_t  pairBytes = ((size_t)NB + 1) * CAP * 4;      // +1 bucket overflow slack
    size_t  featF32   = (size_t)n * 64 * 4;
    size_t  bigBytes  = pairBytes > featF32 ? pairBytes : featF32;
    char*   big       = (char*)carve(bigBytes);          // packed pairs, later hbuf
    int*    pairs     = (int*)big;
    float*  hbuf      = (float*)big;                     // pairs dead by then
    __half* hsA       = (__half*)carve((size_t)(n + 1) * 32 * 2);  // cols 0-31 (+zero row)
    __half* hsB       = (__half*)carve((size_t)(n + 1) * 32 * 2);  // cols 32-63 (+zero row)

    const int* srcIdx = ei;
    const int* dstIdx = ei + E;
    const int scatterBlocks = (E + EPB - 1) / EPB;  // 391
    const int gemmBlocks = (n + 15) / 16;           // 3125
    const int aggBlocks = 2048;                     // grid-stride, phase-aligned

    // --- prep: fixed-capacity bucket scatter -> padded csr, rowinfo, dinv ---
    zero_kernel<<<(NBMAX + 255) / 256, 256, 0, stream>>>(
        bucketCur, NBMAX, (int*)(hsA + (size_t)n * 32), (int*)(hsB + (size_t)n * 32));
    bin_scatter_kernel<<<scatterBlocks, 256, 0, stream>>>(srcIdx, dstIdx, E, NB, bucketCur, pairs);
    build_csr_kernel<<<NB, 256, 0, stream>>>(pairs, bucketCur, NB, n, rowinfo, dinv, csr);

    // --- layer 1: relu(gcn_conv(x, W1, b1)) -> hbuf (fp32) ---
    gemm_scale_kernel<128><<<gemmBlocks, 256, 0, stream>>>(x, W1, dinv, hsA, hsB, n);
    aggregate_kernel<true><<<aggBlocks, 256, 0, stream>>>(hsA, hsB, rowinfo, csr, dinv, b1, hbuf, n);

    // --- layer 2: gcn_conv(hbuf, W2, b2) -> out ---
    gemm_scale_kernel<64><<<gemmBlocks, 256, 0, stream>>>(hbuf, W2, dinv, hsA, hsB, n);
    aggregate_kernel<false><<<aggBlocks, 256, 0, stream>>>(hsA, hsB, rowinfo, csr, dinv, b2, out, n);
}

// Round 21
// 116.086 us; speedup vs baseline: 5.8915x; 1.3951x over previous
//
#include <hip/hip_runtime.h>
#include <hip/hip_fp16.h>

// ---------------------------------------------------------------------------
// 2-layer GCN on MI355X (R21).
//   prep:   fixed-capacity bucket scatter -> padded CSR(byte-offsets)
//           + rowinfo(beg,cnt) + dinv                       (R16 form)
//   layer:  hs = fp16((x@W) * dinv[row])   -- MFMA 16x16x32 f16 gemm (NEW)
//           agg[i] = hs[i] + sum_{s->i} hs[s]               (R16 form)
//           out = agg * dinv[i] + b (+relu)  (fp32)
// R20 lessons: column-split agg was neutral->worse (reverted); gemm1 was
// measured 39.9us VALUBusy 62% MfmaUtil 0 -- readlane gemm is VALU-instr
// bound (~2.25 instr/FMA). R21: gemm on matrix cores. A-frag: lane holds
// X[r0+(l&15)][kt*32+(l>>4)*8+j] (fp32 loads + cvt_pkrtz). B: W staged
// transposed fp16 in LDS (Wt[c][k]) so a lane's frag is one ds_read_b128.
// D (m89-verified): col=lane&15, row=(lane>>4)*4+reg.
// ---------------------------------------------------------------------------

#define NPB_SHIFT 7
#define NPB 128            // nodes per bucket
#define NBMAX 1024         // supports n <= 131072
#define EPB 4096           // edges per scatter block
#define KPB (EPB / 256)    // edges per thread in scatter block
#define EMAX 8192          // LDS csr staging capacity per bucket (padded)
#define CAP 4608           // fixed pairs capacity per bucket (mean+8sigma)
#define CSRSTRIDE 6656     // fixed csr segment per bucket (>= CAP + 128*15+16)

typedef _Float16 f16x8 __attribute__((ext_vector_type(8)));
typedef float f32x4 __attribute__((ext_vector_type(4)));
union F16x8 { f16x8 v; __half2 h[4]; uint4 u; };

__global__ __launch_bounds__(256) void zero_kernel(int* __restrict__ p, int m,
                                                   int* __restrict__ zrow) {
    int i = blockIdx.x * 256 + threadIdx.x;
    if (i < m) p[i] = 0;
    if (blockIdx.x == 0 && threadIdx.x < 32) zrow[threadIdx.x] = 0;   // 128B zero row
}

// Scatter packed edges pk = (src<<7)|(dst&127) into fixed-capacity bucket
// runs. bucketCur ends as per-bucket count.
__global__ __launch_bounds__(256) void bin_scatter_kernel(const int* __restrict__ src,
                                                          const int* __restrict__ dst, int E, int NB,
                                                          int* __restrict__ bucketCur,
                                                          int* __restrict__ pairs) {
    __shared__ int cntA[NBMAX];
    __shared__ int baseB[NBMAX];
    for (int i = threadIdx.x; i < NB; i += 256) cntA[i] = 0;
    __syncthreads();
    int base = blockIdx.x * EPB;
    int pk_[KPB], b_[KPB];
    #pragma unroll
    for (int k = 0; k < KPB; ++k) {
        int i = base + k * 256 + threadIdx.x;
        if (i < E) {
            int s = src[i], d = dst[i];
            pk_[k] = (s << NPB_SHIFT) | (d & (NPB - 1));
            b_[k] = d >> NPB_SHIFT;
            atomicAdd(&cntA[b_[k]], 1);
        } else {
            b_[k] = -1;
        }
    }
    __syncthreads();
    for (int i = threadIdx.x; i < NB; i += 256) {
        int c = cntA[i];
        baseB[i] = c ? atomicAdd(&bucketCur[i], c) : 0;
        cntA[i] = 0;
    }
    __syncthreads();
    #pragma unroll
    for (int k = 0; k < KPB; ++k) {
        if (b_[k] >= 0) {
            int off = atomicAdd(&cntA[b_[k]], 1);
            pairs[b_[k] * CAP + baseB[b_[k]] + off] = pk_[k];
        }
    }
}

// One block per bucket. Segments padded to multiples of 16 slots; pad slots
// hold the zero-row byte offset (n<<7). csr entry = pk & ~127 (= src<<7).
__global__ __launch_bounds__(256) void build_csr_kernel(const int* __restrict__ pairs,
                                                        const int* __restrict__ bucketCnt,
                                                        int NB, int n,
                                                        int2* __restrict__ rowinfo,
                                                        float* __restrict__ dinv,
                                                        int* __restrict__ csr) {
    __shared__ int deg[NPB];
    __shared__ int cur[NPB];
    __shared__ int rowL[NPB];      // padded exclusive prefix
    __shared__ int lcsr[EMAX];
    __shared__ int s_mP;
    int b = blockIdx.x;
    int nodeBase = b << NPB_SHIFT;
    int nNodes = min(NPB, n - nodeBase);
    int eBeg = b * CAP;
    int m = min(bucketCnt[b], CAP);
    int eEnd = eBeg + m;
    int Pb = b * CSRSTRIDE;
    for (int i = threadIdx.x; i < NPB; i += 256) { deg[i] = 0; cur[i] = 0; }
    __syncthreads();
    for (int e = eBeg + threadIdx.x; e < eEnd; e += 256)
        atomicAdd(&deg[pairs[e] & (NPB - 1)], 1);
    __syncthreads();
    if (threadIdx.x < 64) {
        int j0 = threadIdx.x * 2, j1 = j0 + 1;
        int p0 = (deg[j0] + 15) & ~15, p1 = (deg[j1] + 15) & ~15;
        int s = p0 + p1;
        int x = s;
        #pragma unroll
        for (int off = 1; off < 64; off <<= 1) {
            int y = __shfl_up(x, off);
            if ((int)threadIdx.x >= off) x += y;
        }
        int excl = x - s;
        rowL[j0] = excl;
        rowL[j1] = excl + p0;
        if (threadIdx.x == 63) s_mP = x;   // padded total
    }
    __syncthreads();
    int mP = s_mP;
    for (int j = threadIdx.x; j < nNodes; j += 256) {
        rowinfo[nodeBase + j] = make_int2(Pb + rowL[j], (deg[j] + 15) & ~15);
        dinv[nodeBase + j] = 1.0f / sqrtf((float)(deg[j] + 1));  // +1 self-loop
    }
    const int padEnt = n << NPB_SHIFT;   // zero-row byte offset
    if (mP <= EMAX) {
        for (int i = threadIdx.x; i < mP; i += 256) lcsr[i] = padEnt;
        __syncthreads();
        for (int e = eBeg + threadIdx.x; e < eEnd; e += 256) {
            int pk = pairs[e];
            int d = pk & (NPB - 1);
            int off = atomicAdd(&cur[d], 1);
            lcsr[rowL[d] + off] = pk & ~(NPB - 1);
        }
        __syncthreads();
        for (int i = threadIdx.x; i < mP; i += 256) csr[Pb + i] = lcsr[i];
    } else {  // overflow fallback (adversarial): direct global init + scatter
        for (int i = threadIdx.x; i < mP; i += 256) csr[Pb + i] = padEnt;
        __syncthreads();
        for (int e = eBeg + threadIdx.x; e < eEnd; e += 256) {
            int pk = pairs[e];
            int d = pk & (NPB - 1);
            int off = atomicAdd(&cur[d], 1);
            csr[Pb + rowL[d] + off] = pk & ~(NPB - 1);
        }
    }
}

// MFMA gemm: hs[r, c] = fp16( dinv[r] * sum_k X[r,k] * W[k,c] ), 64 cols.
// Block = 4 waves; wave computes a 16-row block (16x64 output) via
// 4 col-tiles x (K/32) k-tiles of mfma_f32_16x16x32_f16.
// W staged once per block into LDS transposed fp16 (Wt[c][k], pad 8) so a
// lane's B-frag (8 consecutive k at col ct*16+(l&15)) is one ds_read_b128.
template <int K>
__global__ __launch_bounds__(256, 2) void gemm_scale_kernel(const float* __restrict__ X,
                                                            const float* __restrict__ W,
                                                            const float* __restrict__ dinv,
                                                            __half* __restrict__ out, int n) {
    __shared__ _Float16 Wt[64][K + 8];
    for (int idx = threadIdx.x; idx < K * 64; idx += 256) {
        int k = idx >> 6, c = idx & 63;
        Wt[c][k] = (_Float16)W[idx];
    }
    __syncthreads();

    const int lane = threadIdx.x & 63;
    const int wid  = threadIdx.x >> 6;
    const int l15  = lane & 15;
    const int lg   = lane >> 4;            // 0..3
    const int r0 = (blockIdx.x * 4 + wid) * 16;
    if (r0 >= n) return;

    // B fragments: [kt][ct], lane holds Wt[ct*16+l15][kt*32 + lg*8 .. +7]
    F16x8 bfr[K / 32][4];
    #pragma unroll
    for (int kt = 0; kt < K / 32; ++kt)
        #pragma unroll
        for (int ct = 0; ct < 4; ++ct)
            bfr[kt][ct].u = *reinterpret_cast<const uint4*>(&Wt[ct * 16 + l15][kt * 32 + lg * 8]);

    f32x4 acc[4] = {{0.f, 0.f, 0.f, 0.f}, {0.f, 0.f, 0.f, 0.f},
                    {0.f, 0.f, 0.f, 0.f}, {0.f, 0.f, 0.f, 0.f}};
    const int arow = min(r0 + l15, n - 1);
    #pragma unroll
    for (int kt = 0; kt < K / 32; ++kt) {
        const float4* xp = reinterpret_cast<const float4*>(
            X + (size_t)arow * K + kt * 32 + lg * 8);
        float4 v0 = xp[0], v1 = xp[1];
        F16x8 a;
        a.h[0] = __float22half2_rn(make_float2(v0.x, v0.y));
        a.h[1] = __float22half2_rn(make_float2(v0.z, v0.w));
        a.h[2] = __float22half2_rn(make_float2(v1.x, v1.y));
        a.h[3] = __float22half2_rn(make_float2(v1.z, v1.w));
        #pragma unroll
        for (int ct = 0; ct < 4; ++ct)
            acc[ct] = __builtin_amdgcn_mfma_f32_16x16x32_f16(a.v, bfr[kt][ct].v, acc[ct], 0, 0, 0);
    }

    // D layout: reg i -> row r0 + lg*4 + i, col ct*16 + l15 (m89 mapping)
    float dv[4];
    #pragma unroll
    for (int i = 0; i < 4; ++i) dv[i] = dinv[min(r0 + lg * 4 + i, n - 1)];
    #pragma unroll
    for (int ct = 0; ct < 4; ++ct) {
        #pragma unroll
        for (int i = 0; i < 4; ++i) {
            int row = r0 + lg * 4 + i;
            if (row < n)
                out[(size_t)row * 64 + ct * 16 + l15] = __float2half_rn(acc[ct][i] * dv[i]);
        }
    }
}

// R16 aggregate: one wave per node; half-wave = one 128B fp16 row per
// edge-slot; 16 slots per iter per half (4 int4 csr loads, 16 gathers).
template <bool RELU>
__global__ __launch_bounds__(256) void aggregate_kernel(const __half* __restrict__ hs,
                                                        const int2* __restrict__ rowinfo,
                                                        const int* __restrict__ csr,
                                                        const float* __restrict__ dinv,
                                                        const float* __restrict__ bias,
                                                        float* __restrict__ out, int n) {
    const int lane = threadIdx.x & 63;
    const int half = lane >> 5;
    const int l32  = lane & 31;
    const int wid  = threadIdx.x >> 6;
    int node = blockIdx.x * 4 + wid;
    if (node >= n) return;

    const char* hsb = (const char*)hs + l32 * 4;   // this lane's column-pair
    int2 info = rowinfo[node];
    const int* base = csr + info.x;
    const int cnt = info.y;                        // multiple of 16
    float a0 = 0.f, a1 = 0.f;
    for (int i = 16 * half; i < cnt; i += 32) {    // halves take alternate 16-blocks
        int4 c0 = *reinterpret_cast<const int4*>(base + i);
        int4 c1 = *reinterpret_cast<const int4*>(base + i + 4);
        int4 c2 = *reinterpret_cast<const int4*>(base + i + 8);
        int4 c3 = *reinterpret_cast<const int4*>(base + i + 12);
        float2 f0 = __half22float2(*(const __half2*)(hsb + c0.x));
        float2 f1 = __half22float2(*(const __half2*)(hsb + c0.y));
        float2 f2 = __half22float2(*(const __half2*)(hsb + c0.z));
        float2 f3 = __half22float2(*(const __half2*)(hsb + c0.w));
        float2 f4 = __half22float2(*(const __half2*)(hsb + c1.x));
        float2 f5 = __half22float2(*(const __half2*)(hsb + c1.y));
        float2 f6 = __half22float2(*(const __half2*)(hsb + c1.z));
        float2 f7 = __half22float2(*(const __half2*)(hsb + c1.w));
        float2 f8 = __half22float2(*(const __half2*)(hsb + c2.x));
        float2 f9 = __half22float2(*(const __half2*)(hsb + c2.y));
        float2 fa = __half22float2(*(const __half2*)(hsb + c2.z));
        float2 fb = __half22float2(*(const __half2*)(hsb + c2.w));
        float2 fc = __half22float2(*(const __half2*)(hsb + c3.x));
        float2 fd = __half22float2(*(const __half2*)(hsb + c3.y));
        float2 fe = __half22float2(*(const __half2*)(hsb + c3.z));
        float2 ff = __half22float2(*(const __half2*)(hsb + c3.w));
        a0 += (((f0.x + f1.x) + (f2.x + f3.x)) + ((f4.x + f5.x) + (f6.x + f7.x)))
            + (((f8.x + f9.x) + (fa.x + fb.x)) + ((fc.x + fd.x) + (fe.x + ff.x)));
        a1 += (((f0.y + f1.y) + (f2.y + f3.y)) + ((f4.y + f5.y) + (f6.y + f7.y)))
            + (((f8.y + f9.y) + (fa.y + fb.y)) + ((fc.y + fd.y) + (fe.y + ff.y)));
    }
    a0 += __shfl_xor(a0, 32);
    a1 += __shfl_xor(a1, 32);
    float2 fs = __half22float2(
        *(const __half2*)((const char*)hs + ((size_t)node << 7) + l32 * 4));
    a0 += fs.x;
    a1 += fs.y;

    if (half == 0) {
        float dv = dinv[node];
        float b0 = bias[2 * l32], b1 = bias[2 * l32 + 1];
        float r0 = fmaf(a0, dv, b0);
        float r1 = fmaf(a1, dv, b1);
        if (RELU) { r0 = fmaxf(r0, 0.f); r1 = fmaxf(r1, 0.f); }
        *reinterpret_cast<float2*>(out + (size_t)node * 64 + 2 * l32) = make_float2(r0, r1);
    }
}

extern "C" void kernel_launch(void* const* d_in, const int* in_sizes, int n_in,
                              void* d_out, int out_size, void* d_ws, size_t ws_size,
                              hipStream_t stream) {
    const float* x  = (const float*)d_in[0];
    const int*   ei = (const int*)d_in[1];   // [2, E] int32
    const float* W1 = (const float*)d_in[2]; // [128, 64]
    const float* b1 = (const float*)d_in[3]; // [64]
    const float* W2 = (const float*)d_in[4]; // [64, 64]
    const float* b2 = (const float*)d_in[5]; // [64]
    float* out = (float*)d_out;

    const int E = in_sizes[1] / 2;   // 1,600,000
    const int n = out_size / 64;     // 50,000
    const int NB = (n + NPB - 1) >> NPB_SHIFT;   // 391 buckets

    char* wsp = (char*)d_ws;
    auto carve = [&](size_t bytes) {
        char* p = wsp;
        wsp += (bytes + 255) & ~(size_t)255;
        return p;
    };
    float*  dinv      = (float*)carve((size_t)n * 4);
    int2*   rowinfo   = (int2*) carve((size_t)n * 8);
    int*    bucketCur = (int*)  carve((size_t)NBMAX * 4);
    int*    csr       = (int*)  carve((size_t)NB * CSRSTRIDE * 4);
    size_t  pairBytes = ((size_t)NB + 1) * CAP * 4;      // +1 bucket overflow slack
    size_t  featF32   = (size_t)n * 64 * 4;
    size_t  bigBytes  = pairBytes > featF32 ? pairBytes : featF32;
    char*   big       = (char*)carve(bigBytes);          // packed pairs, later hbuf
    int*    pairs     = (int*)big;
    float*  hbuf      = (float*)big;                     // pairs dead by then
    __half* hsbuf     = (__half*)carve((size_t)(n + 1) * 64 * 2);  // +1 zero row

    const int* srcIdx = ei;
    const int* dstIdx = ei + E;
    const int scatterBlocks = (E + EPB - 1) / EPB;  // 391
    const int gemmBlocks = (n + 63) / 64;           // 782 (64 rows/block)

    // --- prep: fixed-capacity bucket scatter -> padded csr, rowinfo, dinv ---
    zero_kernel<<<(NBMAX + 255) / 256, 256, 0, stream>>>(bucketCur, NBMAX,
                                                         (int*)(hsbuf + (size_t)n * 64));
    bin_scatter_kernel<<<scatterBlocks, 256, 0, stream>>>(srcIdx, dstIdx, E, NB, bucketCur, pairs);
    build_csr_kernel<<<NB, 256, 0, stream>>>(pairs, bucketCur, NB, n, rowinfo, dinv, csr);

    // --- layer 1: relu(gcn_conv(x, W1, b1)) -> hbuf (fp32) ---
    gemm_scale_kernel<128><<<gemmBlocks, 256, 0, stream>>>(x, W1, dinv, hsbuf, n);
    aggregate_kernel<true><<<(n + 3) / 4, 256, 0, stream>>>(hsbuf, rowinfo, csr, dinv, b1, hbuf, n);

    // --- layer 2: gcn_conv(hbuf, W2, b2) -> out ---
    gemm_scale_kernel<64><<<gemmBlocks, 256, 0, stream>>>(hbuf, W2, dinv, hsbuf, n);
    aggregate_kernel<false><<<(n + 3) / 4, 256, 0, stream>>>(hsbuf, rowinfo, csr, dinv, b2, out, n);
}